// Round 2
// baseline (195.387 us; speedup 1.0000x reference)
//
#include <hip/hip_runtime.h>
#include <hip/hip_bf16.h>
#include <stdint.h>

typedef __attribute__((ext_vector_type(8))) short short8;
typedef __attribute__((ext_vector_type(4))) float f32x4;

__device__ __forceinline__ short f2bf(float f) {
  union { float f; unsigned u; } x; x.f = f;
  unsigned r = (x.u + 0x7FFFu + ((x.u >> 16) & 1u)) >> 16;
  return (short)r;
}

__device__ __forceinline__ short8 cvt8(const float* p) {
  const float4 f0 = *(const float4*)p;
  const float4 f1 = *(const float4*)(p + 4);
  short8 r;
  r[0] = f2bf(f0.x); r[1] = f2bf(f0.y); r[2] = f2bf(f0.z); r[3] = f2bf(f0.w);
  r[4] = f2bf(f1.x); r[5] = f2bf(f1.y); r[6] = f2bf(f1.z); r[7] = f2bf(f1.w);
  return r;
}

// packed weights in d_ws (bf16 bit patterns in shorts):
//   pWin : [3][8ks][8nf][64lane][8]   elems     0 .. 98303
//   pWh  : [3][2][4ks][8nf][64][8]    elems  98304 .. 196607
//   pWout: [3][4ks][16nf][64][8]      elems 196608 .. 294911
__global__ __launch_bounds__(256) void pack_weights(
    const float* __restrict__ Win, const float* __restrict__ Wh,
    const float* __restrict__ Wout, short* __restrict__ o) {
  int gid = blockIdx.x * 256 + threadIdx.x;
  if (gid < 12288) {
    int t = gid / 4096, r = gid % 4096;
    int ks = r / 512, r2 = r % 512, nf = r2 / 64, l = r2 % 64;
    int n = nf * 16 + (l & 15);
    int kb = ks * 32 + (l >> 4) * 8;
#pragma unroll
    for (int i = 0; i < 8; ++i)
      o[gid * 8 + i] = f2bf(Win[(t * 256 + kb + i) * 128 + n]);
  } else if (gid < 24576) {
    int h = gid - 12288;
    int tl = h / 2048, r = h % 2048;
    int ks = r / 512, nf = (r % 512) / 64, l = r % 64;
    int n = nf * 16 + (l & 15);
    int kb = ks * 32 + (l >> 4) * 8;
#pragma unroll
    for (int i = 0; i < 8; ++i)
      o[98304 + h * 8 + i] = f2bf(Wh[(tl * 128 + kb + i) * 128 + n]);
  } else {
    int oo = gid - 24576;
    int t = oo / 4096, r = oo % 4096;
    int ks = r / 1024, nf = (r % 1024) / 64, l = r % 64;
    int n = nf * 16 + (l & 15);
    int kb = ks * 32 + (l >> 4) * 8;
#pragma unroll
    for (int i = 0; i < 8; ++i)
      o[196608 + oo * 8 + i] = f2bf(Wout[(t * 128 + kb + i) * 256 + n]);
  }
}

__global__ __launch_bounds__(256, 2) void fused_towers(
    const int* __restrict__ user, const int* __restrict__ item,
    const float* __restrict__ su, const float* __restrict__ ti,
    const float* __restrict__ bin, const float* __restrict__ bh,
    const float* __restrict__ bout, const short* __restrict__ wp,
    float* __restrict__ out) {
  __shared__ __align__(16) short sW[16384];    // 32KB weight staging
  __shared__ __align__(16) short sAct[16384];  // 32KB: Ha [0,16K)B, Hb [16K,32K)B
  __shared__ float sL[3][64];
  __shared__ float sS[3][64];
  __shared__ int sUid[64];
  __shared__ int sItm[64];

  const int tid = threadIdx.x;
  const int w = tid >> 6, lane = tid & 63;
  const int ar = lane & 15, g = lane >> 4;
  const f32x4 fz = {0.f, 0.f, 0.f, 0.f};

  if (tid < 64) {
    sUid[tid] = user[blockIdx.x * 64 + tid];
    sItm[tid] = item[blockIdx.x * 64 + tid];
  }
  if (tid < 192) { (&sL[0][0])[tid] = 0.f; (&sS[0][0])[tid] = 0.f; }
  __syncthreads();

  const float* uptr[4];
#pragma unroll
  for (int m = 0; m < 4; ++m) uptr[m] = su + (size_t)sUid[m * 16 + ar] * 256;

  char* const Ha = (char*)sAct;
  char* const Hb = (char*)sAct + 16384;

  for (int t = 0; t < 3; ++t) {
    f32x4 acc[4][4];
    // ---------- layer 1: [64x256] @ [256x128] -> Ha (relu + bin) ----------
#pragma unroll
    for (int m = 0; m < 4; ++m) { acc[m][0] = fz; acc[m][1] = fz; }
    for (int half = 0; half < 2; ++half) {
      __syncthreads();
      {
        const uint4* src = (const uint4*)(wp + t * 32768 + half * 16384);
        uint4* dst = (uint4*)sW;
#pragma unroll
        for (int i = 0; i < 8; ++i) dst[tid + i * 256] = src[tid + i * 256];
      }
      __syncthreads();
#pragma unroll
      for (int ksl = 0; ksl < 4; ++ksl) {
        const int K0 = half * 4 + ksl;
        short8 a[4];
#pragma unroll
        for (int m = 0; m < 4; ++m) a[m] = cvt8(uptr[m] + K0 * 32 + g * 8);
#pragma unroll
        for (int nfl = 0; nfl < 2; ++nfl) {
          const short8 b = *(const short8*)((const char*)sW + (ksl * 8 + w * 2 + nfl) * 1024 + lane * 16);
#pragma unroll
          for (int m = 0; m < 4; ++m)
            acc[m][nfl] = __builtin_amdgcn_mfma_f32_16x16x32_bf16(a[m], b, acc[m][nfl], 0, 0, 0);
        }
      }
    }
#pragma unroll
    for (int m = 0; m < 4; ++m)
#pragma unroll
      for (int nfl = 0; nfl < 2; ++nfl) {
        const int col = w * 32 + nfl * 16 + ar;
        const float bv = bin[t * 128 + col];
#pragma unroll
        for (int q = 0; q < 4; ++q) {
          const int r = m * 16 + g * 4 + q;
          const float v = fmaxf(acc[m][nfl][q] + bv, 0.f);
          *(short*)(Ha + r * 256 + ((col * 2) ^ ((r & 7) << 4))) = f2bf(v);
        }
      }
    // ---------- layers 2,3: [64x128] @ [128x128] ----------
#pragma unroll
    for (int L = 0; L < 2; ++L) {
      char* const hin = L ? Hb : Ha;
      char* const hout = L ? Ha : Hb;
#pragma unroll
      for (int m = 0; m < 4; ++m) { acc[m][0] = fz; acc[m][1] = fz; }
      __syncthreads();
      {
        const uint4* src = (const uint4*)(wp + 98304 + (t * 2 + L) * 16384);
        uint4* dst = (uint4*)sW;
#pragma unroll
        for (int i = 0; i < 8; ++i) dst[tid + i * 256] = src[tid + i * 256];
      }
      __syncthreads();
#pragma unroll
      for (int ks = 0; ks < 4; ++ks) {
        short8 a[4];
#pragma unroll
        for (int m = 0; m < 4; ++m) {
          const int r = m * 16 + ar;
          a[m] = *(const short8*)(hin + r * 256 + ((ks * 64 + g * 16) ^ ((r & 7) << 4)));
        }
#pragma unroll
        for (int nfl = 0; nfl < 2; ++nfl) {
          const short8 b = *(const short8*)((const char*)sW + (ks * 8 + w * 2 + nfl) * 1024 + lane * 16);
#pragma unroll
          for (int m = 0; m < 4; ++m)
            acc[m][nfl] = __builtin_amdgcn_mfma_f32_16x16x32_bf16(a[m], b, acc[m][nfl], 0, 0, 0);
        }
      }
#pragma unroll
      for (int m = 0; m < 4; ++m)
#pragma unroll
        for (int nfl = 0; nfl < 2; ++nfl) {
          const int col = w * 32 + nfl * 16 + ar;
          const float bv = bh[(t * 2 + L) * 128 + col];
#pragma unroll
          for (int q = 0; q < 4; ++q) {
            const int r = m * 16 + g * 4 + q;
            const float v = fmaxf(acc[m][nfl][q] + bv, 0.f);
            *(short*)(hout + r * 256 + ((col * 2) ^ ((r & 7) << 4))) = f2bf(v);
          }
        }
    }
    // ---------- layer 4: [64x128] @ [128x256], bias only ----------
#pragma unroll
    for (int m = 0; m < 4; ++m)
#pragma unroll
      for (int n = 0; n < 4; ++n) acc[m][n] = fz;
    for (int half = 0; half < 2; ++half) {
      __syncthreads();
      {
        const uint4* src = (const uint4*)(wp + 196608 + t * 32768 + half * 16384);
        uint4* dst = (uint4*)sW;
#pragma unroll
        for (int i = 0; i < 8; ++i) dst[tid + i * 256] = src[tid + i * 256];
      }
      __syncthreads();
#pragma unroll
      for (int ksl = 0; ksl < 2; ++ksl) {
        const int K0 = half * 2 + ksl;
        short8 a[4];
#pragma unroll
        for (int m = 0; m < 4; ++m) {
          const int r = m * 16 + ar;
          a[m] = *(const short8*)(Ha + r * 256 + ((K0 * 64 + g * 16) ^ ((r & 7) << 4)));
        }
#pragma unroll
        for (int nfl = 0; nfl < 4; ++nfl) {
          const short8 b = *(const short8*)((const char*)sW + (ksl * 16 + w * 4 + nfl) * 1024 + lane * 16);
#pragma unroll
          for (int m = 0; m < 4; ++m)
            acc[m][nfl] = __builtin_amdgcn_mfma_f32_16x16x32_bf16(a[m], b, acc[m][nfl], 0, 0, 0);
        }
      }
    }
    // ---------- tail: logits & score dots, reduce ----------
    float pl[16], ps[16];
#pragma unroll
    for (int i = 0; i < 16; ++i) { pl[i] = 0.f; ps[i] = 0.f; }
#pragma unroll
    for (int m = 0; m < 4; ++m)
#pragma unroll
      for (int nfl = 0; nfl < 4; ++nfl) {
        const int col = w * 64 + nfl * 16 + ar;
        const float bo = bout[t * 256 + col];
#pragma unroll
        for (int q = 0; q < 4; ++q) {
          const int r = m * 16 + g * 4 + q;
          const float x = acc[m][nfl][q] + bo;
          const float kv = ti[(size_t)sUid[r] * 256 + col];
          const float ev = ti[(size_t)sItm[r] * 256 + col];
          pl[m * 4 + q] += x * kv;
          ps[m * 4 + q] += x * ev;
        }
      }
#pragma unroll
    for (int i = 0; i < 16; ++i) {
      float a0 = pl[i], b0 = ps[i];
#pragma unroll
      for (int off = 1; off < 16; off <<= 1) {
        a0 += __shfl_xor(a0, off);
        b0 += __shfl_xor(b0, off);
      }
      pl[i] = a0; ps[i] = b0;
    }
    if (ar == 0) {
#pragma unroll
      for (int m = 0; m < 4; ++m)
#pragma unroll
        for (int q = 0; q < 4; ++q) {
          const int r = m * 16 + g * 4 + q;
          atomicAdd(&sL[t][r], pl[m * 4 + q]);
          atomicAdd(&sS[t][r], ps[m * 4 + q]);
        }
    }
  }
  __syncthreads();
  if (tid < 64) {
    const float l0 = sL[0][tid], l1 = sL[1][tid], l2 = sL[2][tid];
    const float mx = fmaxf(l0, fmaxf(l1, l2));
    const float e0 = __expf(l0 - mx), e1 = __expf(l1 - mx), e2 = __expf(l2 - mx);
    out[blockIdx.x * 64 + tid] =
        (e0 * sS[0][tid] + e1 * sS[1][tid] + e2 * sS[2][tid]) / (e0 + e1 + e2);
  }
}

extern "C" void kernel_launch(void* const* d_in, const int* in_sizes, int n_in,
                              void* d_out, int out_size, void* d_ws, size_t ws_size,
                              hipStream_t stream) {
  const int* user = (const int*)d_in[0];
  const int* item = (const int*)d_in[1];
  const float* su = (const float*)d_in[2];
  const float* ti = (const float*)d_in[3];
  const float* Win = (const float*)d_in[4];
  const float* bin = (const float*)d_in[5];
  const float* Wh = (const float*)d_in[6];
  const float* bh = (const float*)d_in[7];
  const float* Wout = (const float*)d_in[8];
  const float* bout = (const float*)d_in[9];
  float* out = (float*)d_out;
  short* ws = (short*)d_ws;

  hipLaunchKernelGGL(pack_weights, dim3(144), dim3(256), 0, stream, Win, Wh, Wout, ws);
  hipLaunchKernelGGL(fused_towers, dim3(1024), dim3(256), 0, stream,
                     user, item, su, ti, bin, bh, bout, (const short*)ws, out);
}